// Round 29
// baseline (496.855 us; speedup 1.0000x reference)
//
#include <hip/hip_runtime.h>
#include <cstdint>
#include <cstddef>

typedef __bf16 bf16x8 __attribute__((ext_vector_type(8)));
typedef __bf16 bf16x4 __attribute__((ext_vector_type(4)));
typedef float  f32x4  __attribute__((ext_vector_type(4)));

#define TOKENS  4096
#define SEQLEN  2048
#define HID     2048
#define QKV_W   6144
#define UP_W    8192
#define INTER_  4096
#define CVT_MAGIC 0x7bf16c01u

__device__ __forceinline__ void async16(const void* g, void* l) {
  __builtin_amdgcn_global_load_lds(
      (__attribute__((address_space(1))) void*)(g),
      (__attribute__((address_space(3))) void*)(l), 16, 0, 0);
}

// ---------------- fp32 -> bf16 weight convert (grid-stride, skip-if-done) ----------
__global__ __launch_bounds__(256) void cvt_kernel(const float* __restrict__ src,
                                                  __bf16* __restrict__ dst, int n4,
                                                  unsigned* __restrict__ ctl) {
  if (ctl && *ctl == CVT_MAGIC) return;
  const int stride = gridDim.x * 256;
  for (int i = blockIdx.x * 256 + threadIdx.x; i < n4; i += stride) {
    float4 f = ((const float4*)src)[i];
    bf16x4 o;
    o[0] = (__bf16)f.x; o[1] = (__bf16)f.y; o[2] = (__bf16)f.z; o[3] = (__bf16)f.w;
    ((bf16x4*)dst)[i] = o;
  }
  if (ctl && blockIdx.x == 0 && threadIdx.x == 0) *ctl = CVT_MAGIC;
}

// ---------------- rmsnorm: fp32 in -> bf16 out ----------------
__global__ __launch_bounds__(256) void rmsnorm_kernel(const float* __restrict__ x,
                                                      const float* __restrict__ wgt,
                                                      __bf16* __restrict__ out) {
  const int tok = blockIdx.x;
  const int t = threadIdx.x;
  const float4* xr = (const float4*)(x + (long)tok * HID);
  float4 a = xr[t], b = xr[t + 256];
  float ss = a.x*a.x + a.y*a.y + a.z*a.z + a.w*a.w
           + b.x*b.x + b.y*b.y + b.z*b.z + b.w*b.w;
  #pragma unroll
  for (int off = 32; off; off >>= 1) ss += __shfl_xor(ss, off);
  __shared__ float red[4];
  if ((t & 63) == 0) red[t >> 6] = ss;
  __syncthreads();
  float tot = red[0] + red[1] + red[2] + red[3];
  float r = rsqrtf(tot * (1.0f / HID) + 1e-5f);
  const float4* wr = (const float4*)wgt;
  float4 wa = wr[t], wb = wr[t + 256];
  bf16x4 o0, o1;
  o0[0] = (__bf16)(a.x * r * wa.x); o0[1] = (__bf16)(a.y * r * wa.y);
  o0[2] = (__bf16)(a.z * r * wa.z); o0[3] = (__bf16)(a.w * r * wa.w);
  o1[0] = (__bf16)(b.x * r * wb.x); o1[1] = (__bf16)(b.y * r * wb.y);
  o1[2] = (__bf16)(b.z * r * wb.z); o1[3] = (__bf16)(b.w * r * wb.w);
  bf16x4* orow = (bf16x4*)(out + (long)tok * HID);
  orow[t] = o0; orow[t + 256] = o1;
}

// ---------------- OLD BK=64 bf16 GEMM (round-0, verified) -- O, Down, V-proj ----
template<bool OUT_BF16, bool ADD_RES, bool ROPE, bool SILU>
__global__ __launch_bounds__(256) void gemm_bt(const __bf16* __restrict__ A, int lda,
                                               const __bf16* __restrict__ B, int ldb,
                                               void* Cv, int ldc,
                                               const float* __restrict__ Res, int K) {
  __shared__ __align__(16) __bf16 As[128 * 64];
  __shared__ __align__(16) __bf16 Bs[128 * 64];
  const int t = threadIdx.x;
  const int lane = t & 63;
  const int w = t >> 6;
  const int wm = (w >> 1) * 64, wn = (w & 1) * 64;
  const int m0 = blockIdx.y * 128;
  const int n0 = SILU ? blockIdx.x * 64 : blockIdx.x * 128;
  const int sr = t >> 3;
  const int sc = (((t & 7) ^ (sr & 7)) * 8);
  const __bf16* Ag = A + (long)(m0 + sr) * lda + sc;
  const __bf16* Bg = B + (long)(n0 + sr) * ldb + sc;
  char* lA = (char*)As + t * 16;
  char* lB = (char*)Bs + t * 16;
  const int lr = lane & 15;
  const int lq = lane >> 4;
  f32x4 acc[4][4] = {};
  for (int k0 = 0; k0 < K; k0 += 64) {
    __syncthreads();
    #pragma unroll
    for (int c = 0; c < 4; c++)
      async16(Ag + (long)(c * 32) * lda + k0, lA + c * 4096);
    #pragma unroll
    for (int c = 0; c < 4; c++) {
      const long rowoff = SILU ? (long)((c & 1) * INTER_ + (c >> 1) * 32) * ldb
                               : (long)(c * 32) * ldb;
      async16(Bg + rowoff + k0, lB + c * 4096);
    }
    __syncthreads();
    #pragma unroll
    for (int ks = 0; ks < 2; ks++) {
      const int pos = (((ks * 4 + lq) ^ (lr & 7)) * 8);
      bf16x8 af[4], bfr[4];
      #pragma unroll
      for (int i = 0; i < 4; i++)
        af[i]  = *(const bf16x8*)(As + (wm + i * 16 + lr) * 64 + pos);
      #pragma unroll
      for (int j = 0; j < 4; j++)
        bfr[j] = *(const bf16x8*)(Bs + (wn + j * 16 + lr) * 64 + pos);
      #pragma unroll
      for (int i = 0; i < 4; i++)
        #pragma unroll
        for (int j = 0; j < 4; j++)
          acc[i][j] = __builtin_amdgcn_mfma_f32_16x16x32_bf16(af[i], bfr[j], acc[i][j], 0, 0, 0);
    }
  }
  const int lq4 = lq * 4;
  #pragma unroll
  for (int i = 0; i < 4; i++) {
    #pragma unroll
    for (int r = 0; r < 4; r++) {
      const long row = m0 + wm + i * 16 + lq4 + r;
      #pragma unroll
      for (int j = 0; j < 4; j++) {
        const long col = n0 + wn + j * 16 + lr;
        float v = acc[i][j][r];
        if (ADD_RES) v += Res[row * (long)ldc + col];
        if (OUT_BF16) ((__bf16*)Cv)[row * (long)ldc + col] = (__bf16)v;
        else          ((float*)Cv)[row * (long)ldc + col] = v;
      }
    }
  }
}

// ---------------- 8-phase 256x256 pipelined GEMM v3 (verified 983 TF) -- QK, Up -------
template<bool ROPE, bool SILU>
__global__ __launch_bounds__(512, 2) void gemm8p(const __bf16* __restrict__ A, int lda,
                                                 const __bf16* __restrict__ B, int ldb,
                                                 void* Cv, int ldc, int K) {
  __shared__ __align__(16) __bf16 As[2 * 16384];   // 2 x 32 KiB
  __shared__ __align__(16) __bf16 Bs[2 * 16384];   // 2 x 32 KiB
  const int tid  = threadIdx.x;
  const int lane = tid & 63;
  const int w    = tid >> 6;
  const int wm2  = w >> 2;        // 0..1
  const int wn4  = w & 3;         // 0..3
  const int lr   = lane & 15;
  const int lq   = lane >> 4;
  const int m0   = blockIdx.y * 256;
  const int n0   = ROPE ? blockIdx.x * 256 : 0;
  const int n0c  = SILU ? blockIdx.x * 128 : 0;

  const long r0 = tid >> 3;
  const int  e  = (((tid & 7) ^ ((int)r0 & 7)) * 8);
  const __bf16* Ap0 = A + (long)(m0 + r0) * lda + e;
  long br0, br1, bhs;
  if (ROPE) {
    br0 = n0 + 64 * (((int)r0 >> 5) & 3) + ((int)r0 & 31);
    br1 = n0 + 64 * ((((int)r0 + 64) >> 5) & 3) + ((int)r0 & 31);
    bhs = 32 * (long)ldb;
  } else {
    br0 = n0c + r0;
    br1 = n0c + r0 + 64;
    bhs = (long)INTER_ * ldb;
  }
  const __bf16* Bp0 = B + br0 * ldb + e;
  const __bf16* Bp1 = B + br1 * ldb + e;
  char* sA = (char*)As;
  char* sB = (char*)Bs;
  const int tid16 = tid * 16;

#define STAGE_A(h_, nb_, kk_) do {                                                     \
    async16(Ap0 + (long)((h_) * 128) * lda + (kk_),      sA + (nb_)*32768 + (h_)*16384 + tid16);        \
    async16(Ap0 + (long)((h_) * 128 + 64) * lda + (kk_), sA + (nb_)*32768 + (h_)*16384 + 8192 + tid16); \
  } while (0)
#define STAGE_B(h_, nb_, kk_) do {                                                     \
    async16(Bp0 + (h_) * bhs + (kk_), sB + (nb_)*32768 + (h_)*16384 + tid16);          \
    async16(Bp1 + (h_) * bhs + (kk_), sB + (nb_)*32768 + (h_)*16384 + 8192 + tid16);   \
  } while (0)

  const int ch0 = ((lq ^ (lr & 7)) * 16);
  const int ch1 = (((4 + lq) ^ (lr & 7)) * 16);
  const int abase = (wm2 * 64 + lr) * 128;
  const int bbase = (wn4 * 32 + lr) * 128;

  f32x4 acc[8][4] = {};
  bf16x8 af[4][2], bfr[4][2];
  const int NT = K >> 6;

#define LOAD_A(mh_) do {                                                               \
    _Pragma("unroll")                                                                  \
    for (int i = 0; i < 4; i++) {                                                      \
      af[i][0] = *(const bf16x8*)(Ab + abase + (mh_)*16384 + i*2048 + ch0);            \
      af[i][1] = *(const bf16x8*)(Ab + abase + (mh_)*16384 + i*2048 + ch1);            \
    } } while (0)
#define LOAD_B(nh_) do {                                                               \
    _Pragma("unroll")                                                                  \
    for (int j = 0; j < 2; j++) {                                                      \
      bfr[(nh_)*2 + j][0] = *(const bf16x8*)(Bb + bbase + (nh_)*16384 + j*2048 + ch0); \
      bfr[(nh_)*2 + j][1] = *(const bf16x8*)(Bb + bbase + (nh_)*16384 + j*2048 + ch1); \
    } } while (0)
#define MFMA_Q(mh_, nh_) do {                                                          \
    __builtin_amdgcn_s_setprio(1);                                                     \
    _Pragma("unroll")                                                                  \
    for (int ks = 0; ks < 2; ks++)                                                     \
      _Pragma("unroll")                                                                \
      for (int i = 0; i < 4; i++)                                                      \
        _Pragma("unroll")                                                              \
        for (int j = 0; j < 2; j++)                                                    \
          acc[(mh_)*4 + i][(nh_)*2 + j] = __builtin_amdgcn_mfma_f32_16x16x32_bf16(     \
              af[i][ks], bfr[(nh_)*2 + j][ks], acc[(mh_)*4 + i][(nh_)*2 + j], 0, 0, 0);\
    __builtin_amdgcn_s_setprio(0);                                                     \
  } while (0)
#define SBAR() do { __builtin_amdgcn_sched_barrier(0);                                 \
    __builtin_amdgcn_s_barrier(); __builtin_amdgcn_sched_barrier(0); } while (0)
#define LGKM0() do { asm volatile("s_waitcnt lgkmcnt(0)" ::: "memory");                \
    __builtin_amdgcn_sched_barrier(0); } while (0)

  STAGE_A(0, 0, 0); STAGE_B(0, 0, 0); STAGE_B(1, 0, 0); STAGE_A(1, 0, 0);
  asm volatile("s_waitcnt vmcnt(4)" ::: "memory");
  SBAR();

  for (int T = 0; T < NT; ++T) {
    const int cb = T & 1, nb = cb ^ 1;
    const int kk = (T + 1) << 6;
    const bool st = (T + 1 < NT);
    const char* Ab = (const char*)As + cb * 32768;
    const char* Bb = (const char*)Bs + cb * 32768;
    LOAD_A(0); LOAD_B(0);
    if (st) { STAGE_A(0, nb, kk); STAGE_B(0, nb, kk); }
    SBAR(); LGKM0();
    MFMA_Q(0, 0);
    if (st) asm volatile("s_waitcnt vmcnt(6)" ::: "memory");
    else    asm volatile("s_waitcnt vmcnt(2)" ::: "memory");
    SBAR();
    LOAD_B(1);
    if (st) STAGE_B(1, nb, kk);
    SBAR(); LGKM0();
    MFMA_Q(0, 1);
    if (st) asm volatile("s_waitcnt vmcnt(6)" ::: "memory");
    else    asm volatile("s_waitcnt vmcnt(0)" ::: "memory");
    SBAR();
    LOAD_A(1);
    if (st) STAGE_A(1, nb, kk);
    SBAR(); LGKM0();
    MFMA_Q(1, 0);
    SBAR();
    MFMA_Q(1, 1);
    if (st) asm volatile("s_waitcnt vmcnt(4)" ::: "memory");
    SBAR();
  }
#undef STAGE_A
#undef STAGE_B
#undef LOAD_A
#undef LOAD_B
#undef MFMA_Q
#undef SBAR
#undef LGKM0

  const int lq4 = lq * 4;
  if (ROPE) {
    if (n0 < 4096) {
      const float invf0 = exp2f((float)(lr)      * -0.41524101186092029f);
      const float invf1 = exp2f((float)(16 + lr) * -0.41524101186092029f);
      #pragma unroll
      for (int mi = 0; mi < 8; mi++) {
        #pragma unroll
        for (int r = 0; r < 4; r++) {
          const long row = m0 + (mi >> 2) * 128 + wm2 * 64 + (mi & 3) * 16 + lq4 + r;
          const float s = (float)(int)(row & (SEQLEN - 1));
          __bf16* crow = (__bf16*)Cv + row * (long)ldc + n0 + wn4 * 64 + lr;
          #pragma unroll
          for (int nj = 0; nj < 2; nj++) {
            float x1 = acc[mi][nj][r], x2 = acc[mi][nj + 2][r];
            float ang = s * (nj ? invf1 : invf0);
            float sn, cs;
            __sincosf(ang, &sn, &cs);
            crow[nj * 16]      = (__bf16)(x1 * cs - x2 * sn);
            crow[nj * 16 + 32] = (__bf16)(x2 * cs + x1 * sn);
          }
        }
      }
    } else {
      #pragma unroll
      for (int mi = 0; mi < 8; mi++) {
        #pragma unroll
        for (int r = 0; r < 4; r++) {
          const long row = m0 + (mi >> 2) * 128 + wm2 * 64 + (mi & 3) * 16 + lq4 + r;
          __bf16* crow = (__bf16*)Cv + row * (long)ldc + n0 + wn4 * 64 + lr;
          #pragma unroll
          for (int njf = 0; njf < 4; njf++)
            crow[(njf >> 1) * 32 + (njf & 1) * 16] = (__bf16)acc[mi][njf][r];
        }
      }
    }
  } else {  // SILU
    #pragma unroll
    for (int mi = 0; mi < 8; mi++) {
      #pragma unroll
      for (int r = 0; r < 4; r++) {
        const long row = m0 + (mi >> 2) * 128 + wm2 * 64 + (mi & 3) * 16 + lq4 + r;
        #pragma unroll
        for (int nj = 0; nj < 2; nj++) {
          const long col = n0c + wn4 * 32 + nj * 16 + lr;
          float g = acc[mi][nj][r];
          float v = acc[mi][nj + 2][r];
          float sg = g / (1.0f + __expf(-g));
          ((__bf16*)Cv)[row * (long)ldc + col] = (__bf16)(sg * v);
        }
      }
    }
  }
}

// ---------------- flash attention v7: 128 q-rows/block, two stripes per wave --------
// Verified rounds 24-28: 515.0 / 496.8 / 497.5 / 513.8 / 496.7 us total. Each wave owns
// stripes A (q0+w*16) and B (q0+64+w*16); K/V loads, V-staging, barriers, kv loop
// SHARED; QK/softmax/P-write/PV duplicated per stripe with statically-named state.
// q0 multiple of 128 -> both stripes in one 512-causal-block; NT even. Pbb 16KB.
__global__ __launch_bounds__(256) void attn_kernel(const __bf16* __restrict__ qkv,
                                                   __bf16* __restrict__ ctx) {
  const int qt   = blockIdx.x;        // 0..15
  const int head = blockIdx.y;
  const int b    = blockIdx.z;
  const int w    = threadIdx.x >> 6;
  const int lane = threadIdx.x & 63;
  const int lr = lane & 15;
  const int lq = lane >> 4;
  const int q0   = qt * 128;
  const int blk0 = q0 & ~511;
  const int nkv  = q0 + 128 - blk0;   // 128..512, multiple of 128
  const int NT   = nkv >> 5;          // 4..16, even
  const long tok0 = (long)b * SEQLEN;

  const int qrowA = q0 + w * 16 + lr;
  const long qoffA = (tok0 + qrowA) * QKV_W + head * 64 + lq * 8;
  bf16x8 qa0 = *(const bf16x8*)(qkv + qoffA);
  bf16x8 qa1 = *(const bf16x8*)(qkv + qoffA + 32);
  const long qoffB = qoffA + (long)64 * QKV_W;
  bf16x8 qb0 = *(const bf16x8*)(qkv + qoffB);
  bf16x8 qb1 = *(const bf16x8*)(qkv + qoffB + 32);

  __shared__ __align__(16) char VTb[8192];    // V^T: d-rows of 128B, 2 kv-halves
  __shared__ __align__(16) char Pbb[16384];   // [w][stripe][16 q][128B]

  const __bf16* kp = qkv + (tok0 + blk0 + lr) * QKV_W + HID + head * 64 + lq * 8;
  const int skv = threadIdx.x & 31;
  const int sd0 = (threadIdx.x >> 5) * 8;
  const __bf16* vp = qkv + (tok0 + blk0 + skv) * QKV_W + 2 * HID + head * 64 + sd0;

  bf16x8 ka[2][2], kb[2][2];

#define LOADK(KN, tk) do { \
    KN[0][0] = *(const bf16x8*)(kp + (long)(tk) * QKV_W); \
    KN[0][1] = *(const bf16x8*)(kp + (long)(tk) * QKV_W + 32); \
    KN[1][0] = *(const bf16x8*)(kp + (long)((tk) + 16) * QKV_W); \
    KN[1][1] = *(const bf16x8*)(kp + (long)((tk) + 16) * QKV_W + 32); \
  } while (0)

#define WRITEV(vr_, hb_) do { \
    const int c_ = (hb_) * 4 + (skv >> 3); \
    char* vb_ = VTb + sd0 * 128 + ((skv & 7) * 2); \
    _Pragma("unroll") \
    for (int i_ = 0; i_ < 8; i_++) \
      *(__bf16*)(vb_ + i_ * 128 + ((c_ ^ i_) * 16)) = vr_[i_]; \
  } while (0)

  LOADK(ka, 0);
  {
    bf16x8 vr0 = *(const bf16x8*)(vp);
    WRITEV(vr0, 0);
  }
  __syncthreads();

  float mA[4], lA_[4], mB[4], lB_[4];
  f32x4 oA[4] = {}, oB[4] = {};
  #pragma unroll
  for (int r = 0; r < 4; r++) { mA[r] = -1e30f; lA_[r] = 0.0f; mB[r] = -1e30f; lB_[r] = 0.0f; }
  const int myrowA = q0 + w * 16 + lq * 4;
  const int myrowB = myrowA + 64;

  // one stripe's softmax + P-write: S regs (sx0,sx1) -> m/l update, P into Pbb stripe
#define SMAX_P(sx0, sx1, m_, l_, myrow_, soff_) do { \
    float p0[4], p1[4], alpha[4]; \
    _Pragma("unroll") \
    for (int r = 0; r < 4; r++) { \
      float v0 = sx0[r] * 0.125f, v1 = sx1[r] * 0.125f; \
      v0 = (kpos0_      <= (myrow_) + r) ? v0 : -1e30f; \
      v1 = (kpos0_ + 16 <= (myrow_) + r) ? v1 : -1e30f; \
      float mx = fmaxf(v0, v1); \
      mx = fmaxf(mx, __shfl_xor(mx, 1)); \
      mx = fmaxf(mx, __shfl_xor(mx, 2)); \
      mx = fmaxf(mx, __shfl_xor(mx, 4)); \
      mx = fmaxf(mx, __shfl_xor(mx, 8)); \
      float mn = fmaxf(m_[r], mx); \
      alpha[r] = __expf(m_[r] - mn); \
      m_[r] = mn; \
      p0[r] = __expf(v0 - mn); \
      p1[r] = __expf(v1 - mn); \
      float rs = p0[r] + p1[r]; \
      rs += __shfl_xor(rs, 1); rs += __shfl_xor(rs, 2); \
      rs += __shfl_xor(rs, 4); rs += __shfl_xor(rs, 8); \
      l_[r] = l_[r] * alpha[r] + rs; \
      alpha_##sx0[r] = alpha[r]; \
    } \
    { \
      char* pw_ = Pbb + w * 4096 + (soff_) + (lq * 4) * 128 + ((lr & 7) * 2); \
      const int cl_ = hb_ * 4 + (lr >> 3); \
      _Pragma("unroll") \
      for (int r = 0; r < 4; r++) { \
        const int q7_ = (lq * 4 + r) & 7; \
        *(__bf16*)(pw_ + r * 128 + (((cl_    ) ^ q7_) * 16)) = (__bf16)p0[r]; \
        *(__bf16*)(pw_ + r * 128 + (((cl_ + 2) ^ q7_) * 16)) = (__bf16)p1[r]; \
      } \
    } \
  } while (0)

#define ITER(t_, KC, KN) { \
    const int hb_ = (t_) & 1; \
    const int tkn_ = ((t_) + 1) * 32; \
    const bool more_ = ((t_) + 1 < NT); \
    bf16x8 vr_ = {}; \
    if (more_) { LOADK(KN, tkn_); vr_ = *(const bf16x8*)(vp + (long)tkn_ * QKV_W); } \
    f32x4 sa0 = {0.f,0.f,0.f,0.f}, sa1 = {0.f,0.f,0.f,0.f}; \
    f32x4 sb0 = {0.f,0.f,0.f,0.f}, sb1 = {0.f,0.f,0.f,0.f}; \
    sa0 = __builtin_amdgcn_mfma_f32_16x16x32_bf16(qa0, KC[0][0], sa0, 0, 0, 0); \
    sa0 = __builtin_amdgcn_mfma_f32_16x16x32_bf16(qa1, KC[0][1], sa0, 0, 0, 0); \
    sa1 = __builtin_amdgcn_mfma_f32_16x16x32_bf16(qa0, KC[1][0], sa1, 0, 0, 0); \
    sa1 = __builtin_amdgcn_mfma_f32_16x16x32_bf16(qa1, KC[1][1], sa1, 0, 0, 0); \
    sb0 = __builtin_amdgcn_mfma_f32_16x16x32_bf16(qb0, KC[0][0], sb0, 0, 0, 0); \
    sb0 = __builtin_amdgcn_mfma_f32_16x16x32_bf16(qb1, KC[0][1], sb0, 0, 0, 0); \
    sb1 = __builtin_amdgcn_mfma_f32_16x16x32_bf16(qb0, KC[1][0], sb1, 0, 0, 0); \
    sb1 = __builtin_amdgcn_mfma_f32_16x16x32_bf16(qb1, KC[1][1], sb1, 0, 0, 0); \
    const int kpos0_ = blk0 + (t_) * 32 + lr; \
    float alpha_sa0[4], alpha_sb0[4]; \
    SMAX_P(sa0, sa1, mA, lA_, myrowA, 0); \
    SMAX_P(sb0, sb1, mB, lB_, myrowB, 2048); \
    _Pragma("unroll") \
    for (int dt = 0; dt < 4; dt++) \
      _Pragma("unroll") \
      for (int r = 0; r < 4; r++) { \
        oA[dt][r] *= alpha_sa0[r]; \
        oB[dt][r] *= alpha_sb0[r]; \
      } \
    asm volatile("s_waitcnt lgkmcnt(0)" ::: "memory"); \
    const int swz_ = ((hb_ * 4 + lq) ^ (lr & 7)) * 16; \
    bf16x8 pfA_ = *(const bf16x8*)(Pbb + w * 4096 + lr * 128 + swz_); \
    bf16x8 pfB_ = *(const bf16x8*)(Pbb + w * 4096 + 2048 + lr * 128 + swz_); \
    _Pragma("unroll") \
    for (int dt = 0; dt < 4; dt++) { \
      bf16x8 vf_ = *(const bf16x8*)(VTb + (dt * 16 + lr) * 128 + swz_); \
      oA[dt] = __builtin_amdgcn_mfma_f32_16x16x32_bf16(pfA_, vf_, oA[dt], 0, 0, 0); \
      oB[dt] = __builtin_amdgcn_mfma_f32_16x16x32_bf16(pfB_, vf_, oB[dt], 0, 0, 0); \
    } \
    __syncthreads(); \
    if (more_) WRITEV(vr_, hb_ ^ 1); \
    __syncthreads(); \
  }

  for (int t2 = 0; t2 < NT; t2 += 2) {
    ITER(t2, ka, kb)
    ITER(t2 + 1, kb, ka)
  }
#undef ITER
#undef SMAX_P
#undef LOADK
#undef WRITEV

  #pragma unroll
  for (int r = 0; r < 4; r++) {
    float invA = 1.0f / lA_[r];
    float invB = 1.0f / lB_[r];
    long obaseA = (tok0 + myrowA + r) * HID + head * 64;
    long obaseB = (tok0 + myrowB + r) * HID + head * 64;
    #pragma unroll
    for (int dt = 0; dt < 4; dt++) {
      ctx[obaseA + dt * 16 + lr] = (__bf16)(oA[dt][r] * invA);
      ctx[obaseB + dt * 16 + lr] = (__bf16)(oB[dt][r] * invB);
    }
  }
}

extern "C" void kernel_launch(void* const* d_in, const int* in_sizes, int n_in,
                              void* d_out, int out_size, void* d_ws, size_t ws_size,
                              hipStream_t stream) {
  const float* x      = (const float*)d_in[0];
  const float* anw    = (const float*)d_in[1];
  const float* fnw    = (const float*)d_in[2];
  const float* w_qkv  = (const float*)d_in[3];
  const float* w_o    = (const float*)d_in[4];
  const float* w_up   = (const float*)d_in[5];
  const float* w_down = (const float*)d_in[6];
  float* out = (float*)d_out;

  const size_t MiB = 1048576;
  char* wsb = (char*)d_ws;
  __bf16* ABUF = (__bf16*)wsb;                   // 16 MiB: h1 / ctx / h2
  __bf16* QKV  = (__bf16*)(wsb + 16 * MiB);      // 48 MiB: qkv; later act (32 MiB)
  __bf16* ACT  = QKV;

  // Persistent converted-weight layout (needs 144 MiB + flags); falls back to the
  // old transient single-scratch layout if the workspace is too small.
  const size_t NEED = 144 * MiB + 64;
  const bool persist = (ws_size >= NEED);
  __bf16 *WQKV, *WO, *WUP, *WDOWN;
  unsigned* CTL = nullptr;
  if (persist) {
    WQKV  = (__bf16*)(wsb + 64 * MiB);   // 24 MiB
    WO    = (__bf16*)(wsb + 88 * MiB);   //  8 MiB
    WUP   = (__bf16*)(wsb + 96 * MiB);   // 32 MiB
    WDOWN = (__bf16*)(wsb + 128 * MiB);  // 16 MiB
    CTL   = (unsigned*)(wsb + 144 * MiB);
  } else {
    __bf16* WBUF = (__bf16*)(wsb + (size_t)83886080);
    WQKV = WO = WUP = WDOWN = WBUF;
  }

  // attention half
  rmsnorm_kernel<<<TOKENS, 256, 0, stream>>>(x, anw, ABUF);
  cvt_kernel<<<2048, 256, 0, stream>>>(w_qkv, WQKV, QKV_W * HID / 4,
                                       persist ? CTL + 0 : nullptr);
  // Q,K (rope fused) via gemm8p v3: grid 16x16 = 256 blocks = exactly 1 round
  gemm8p<true, false><<<dim3(4096 / 256, TOKENS / 256), 512, 0, stream>>>(
      ABUF, HID, WQKV, HID, (void*)QKV, QKV_W, HID);
  // V (plain) via old kernel: grid 16x32 = 512 blocks, full chip
  gemm_bt<true, false, false, false><<<dim3(HID / 128, TOKENS / 128), 256, 0, stream>>>(
      ABUF, HID, WQKV + (size_t)4096 * HID, HID, (void*)(QKV + 4096), QKV_W, nullptr, HID);
  attn_kernel<<<dim3(SEQLEN / 128, 32, 2), 256, 0, stream>>>(QKV, ABUF);
  cvt_kernel<<<2048, 256, 0, stream>>>(w_o, WO, HID * HID / 4,
                                       persist ? CTL + 1 : nullptr);
  gemm_bt<false, true, false, false><<<dim3(HID / 128, TOKENS / 128), 256, 0, stream>>>(
      ABUF, HID, WO, HID, (void*)out, HID, x, HID);   // out = x + ctx@w_o^T

  // ffn half
  rmsnorm_kernel<<<TOKENS, 256, 0, stream>>>(out, fnw, ABUF);
  cvt_kernel<<<2048, 256, 0, stream>>>(w_up, WUP, UP_W * HID / 4,
                                       persist ? CTL + 2 : nullptr);
  // fused up+silu via gemm8p v3: grid 32x16 = 512 blocks = 2 exact rounds
  gemm8p<false, true><<<dim3(INTER_ / 128, TOKENS / 256), 512, 0, stream>>>(
      ABUF, HID, WUP, HID, (void*)ACT, INTER_, HID);
  cvt_kernel<<<2048, 256, 0, stream>>>(w_down, WDOWN, HID * INTER_ / 4,
                                       persist ? CTL + 3 : nullptr);
  gemm_bt<false, true, false, false><<<dim3(HID / 128, TOKENS / 128), 256, 0, stream>>>(
      ACT, INTER_, WDOWN, INTER_, (void*)out, HID, out, INTER_); // out += act@w_down^T
}

// Round 31
// 495.910 us; speedup vs baseline: 1.0019x; 1.0019x over previous
//
#include <hip/hip_runtime.h>
#include <cstdint>
#include <cstddef>

typedef __bf16 bf16x8 __attribute__((ext_vector_type(8)));
typedef __bf16 bf16x4 __attribute__((ext_vector_type(4)));
typedef float  f32x4  __attribute__((ext_vector_type(4)));

#define TOKENS  4096
#define SEQLEN  2048
#define HID     2048
#define QKV_W   6144
#define UP_W    8192
#define INTER_  4096
#define CVT_MAGIC 0x7bf16c01u

__device__ __forceinline__ void async16(const void* g, void* l) {
  __builtin_amdgcn_global_load_lds(
      (__attribute__((address_space(1))) void*)(g),
      (__attribute__((address_space(3))) void*)(l), 16, 0, 0);
}

// ---------------- fp32 -> bf16 weight convert (grid-stride, skip-if-done) ----------
__global__ __launch_bounds__(256) void cvt_kernel(const float* __restrict__ src,
                                                  __bf16* __restrict__ dst, int n4,
                                                  unsigned* __restrict__ ctl) {
  if (ctl && *ctl == CVT_MAGIC) return;
  const int stride = gridDim.x * 256;
  for (int i = blockIdx.x * 256 + threadIdx.x; i < n4; i += stride) {
    float4 f = ((const float4*)src)[i];
    bf16x4 o;
    o[0] = (__bf16)f.x; o[1] = (__bf16)f.y; o[2] = (__bf16)f.z; o[3] = (__bf16)f.w;
    ((bf16x4*)dst)[i] = o;
  }
  if (ctl && blockIdx.x == 0 && threadIdx.x == 0) *ctl = CVT_MAGIC;
}

// ---------------- rmsnorm: fp32 in -> bf16 out ----------------
__global__ __launch_bounds__(256) void rmsnorm_kernel(const float* __restrict__ x,
                                                      const float* __restrict__ wgt,
                                                      __bf16* __restrict__ out) {
  const int tok = blockIdx.x;
  const int t = threadIdx.x;
  const float4* xr = (const float4*)(x + (long)tok * HID);
  float4 a = xr[t], b = xr[t + 256];
  float ss = a.x*a.x + a.y*a.y + a.z*a.z + a.w*a.w
           + b.x*b.x + b.y*b.y + b.z*b.z + b.w*b.w;
  #pragma unroll
  for (int off = 32; off; off >>= 1) ss += __shfl_xor(ss, off);
  __shared__ float red[4];
  if ((t & 63) == 0) red[t >> 6] = ss;
  __syncthreads();
  float tot = red[0] + red[1] + red[2] + red[3];
  float r = rsqrtf(tot * (1.0f / HID) + 1e-5f);
  const float4* wr = (const float4*)wgt;
  float4 wa = wr[t], wb = wr[t + 256];
  bf16x4 o0, o1;
  o0[0] = (__bf16)(a.x * r * wa.x); o0[1] = (__bf16)(a.y * r * wa.y);
  o0[2] = (__bf16)(a.z * r * wa.z); o0[3] = (__bf16)(a.w * r * wa.w);
  o1[0] = (__bf16)(b.x * r * wb.x); o1[1] = (__bf16)(b.y * r * wb.y);
  o1[2] = (__bf16)(b.z * r * wb.z); o1[3] = (__bf16)(b.w * r * wb.w);
  bf16x4* orow = (bf16x4*)(out + (long)tok * HID);
  orow[t] = o0; orow[t + 256] = o1;
}

// ---------------- OLD BK=64 bf16 GEMM (round-0, verified) -- O, Down, V-proj ----
template<bool OUT_BF16, bool ADD_RES, bool ROPE, bool SILU>
__global__ __launch_bounds__(256) void gemm_bt(const __bf16* __restrict__ A, int lda,
                                               const __bf16* __restrict__ B, int ldb,
                                               void* Cv, int ldc,
                                               const float* __restrict__ Res, int K) {
  __shared__ __align__(16) __bf16 As[128 * 64];
  __shared__ __align__(16) __bf16 Bs[128 * 64];
  const int t = threadIdx.x;
  const int lane = t & 63;
  const int w = t >> 6;
  const int wm = (w >> 1) * 64, wn = (w & 1) * 64;
  const int m0 = blockIdx.y * 128;
  const int n0 = SILU ? blockIdx.x * 64 : blockIdx.x * 128;
  const int sr = t >> 3;
  const int sc = (((t & 7) ^ (sr & 7)) * 8);
  const __bf16* Ag = A + (long)(m0 + sr) * lda + sc;
  const __bf16* Bg = B + (long)(n0 + sr) * ldb + sc;
  char* lA = (char*)As + t * 16;
  char* lB = (char*)Bs + t * 16;
  const int lr = lane & 15;
  const int lq = lane >> 4;
  f32x4 acc[4][4] = {};
  for (int k0 = 0; k0 < K; k0 += 64) {
    __syncthreads();
    #pragma unroll
    for (int c = 0; c < 4; c++)
      async16(Ag + (long)(c * 32) * lda + k0, lA + c * 4096);
    #pragma unroll
    for (int c = 0; c < 4; c++) {
      const long rowoff = SILU ? (long)((c & 1) * INTER_ + (c >> 1) * 32) * ldb
                               : (long)(c * 32) * ldb;
      async16(Bg + rowoff + k0, lB + c * 4096);
    }
    __syncthreads();
    #pragma unroll
    for (int ks = 0; ks < 2; ks++) {
      const int pos = (((ks * 4 + lq) ^ (lr & 7)) * 8);
      bf16x8 af[4], bfr[4];
      #pragma unroll
      for (int i = 0; i < 4; i++)
        af[i]  = *(const bf16x8*)(As + (wm + i * 16 + lr) * 64 + pos);
      #pragma unroll
      for (int j = 0; j < 4; j++)
        bfr[j] = *(const bf16x8*)(Bs + (wn + j * 16 + lr) * 64 + pos);
      #pragma unroll
      for (int i = 0; i < 4; i++)
        #pragma unroll
        for (int j = 0; j < 4; j++)
          acc[i][j] = __builtin_amdgcn_mfma_f32_16x16x32_bf16(af[i], bfr[j], acc[i][j], 0, 0, 0);
    }
  }
  const int lq4 = lq * 4;
  #pragma unroll
  for (int i = 0; i < 4; i++) {
    #pragma unroll
    for (int r = 0; r < 4; r++) {
      const long row = m0 + wm + i * 16 + lq4 + r;
      #pragma unroll
      for (int j = 0; j < 4; j++) {
        const long col = n0 + wn + j * 16 + lr;
        float v = acc[i][j][r];
        if (ADD_RES) v += Res[row * (long)ldc + col];
        if (OUT_BF16) ((__bf16*)Cv)[row * (long)ldc + col] = (__bf16)v;
        else          ((float*)Cv)[row * (long)ldc + col] = v;
      }
    }
  }
}

// ---------------- 8-phase 256x256 pipelined GEMM v3 (verified 983 TF) -- QK, Up -------
template<bool ROPE, bool SILU>
__global__ __launch_bounds__(512, 2) void gemm8p(const __bf16* __restrict__ A, int lda,
                                                 const __bf16* __restrict__ B, int ldb,
                                                 void* Cv, int ldc, int K) {
  __shared__ __align__(16) __bf16 As[2 * 16384];   // 2 x 32 KiB
  __shared__ __align__(16) __bf16 Bs[2 * 16384];   // 2 x 32 KiB
  const int tid  = threadIdx.x;
  const int lane = tid & 63;
  const int w    = tid >> 6;
  const int wm2  = w >> 2;        // 0..1
  const int wn4  = w & 3;         // 0..3
  const int lr   = lane & 15;
  const int lq   = lane >> 4;
  const int m0   = blockIdx.y * 256;
  const int n0   = ROPE ? blockIdx.x * 256 : 0;
  const int n0c  = SILU ? blockIdx.x * 128 : 0;

  const long r0 = tid >> 3;
  const int  e  = (((tid & 7) ^ ((int)r0 & 7)) * 8);
  const __bf16* Ap0 = A + (long)(m0 + r0) * lda + e;
  long br0, br1, bhs;
  if (ROPE) {
    br0 = n0 + 64 * (((int)r0 >> 5) & 3) + ((int)r0 & 31);
    br1 = n0 + 64 * ((((int)r0 + 64) >> 5) & 3) + ((int)r0 & 31);
    bhs = 32 * (long)ldb;
  } else {
    br0 = n0c + r0;
    br1 = n0c + r0 + 64;
    bhs = (long)INTER_ * ldb;
  }
  const __bf16* Bp0 = B + br0 * ldb + e;
  const __bf16* Bp1 = B + br1 * ldb + e;
  char* sA = (char*)As;
  char* sB = (char*)Bs;
  const int tid16 = tid * 16;

#define STAGE_A(h_, nb_, kk_) do {                                                     \
    async16(Ap0 + (long)((h_) * 128) * lda + (kk_),      sA + (nb_)*32768 + (h_)*16384 + tid16);        \
    async16(Ap0 + (long)((h_) * 128 + 64) * lda + (kk_), sA + (nb_)*32768 + (h_)*16384 + 8192 + tid16); \
  } while (0)
#define STAGE_B(h_, nb_, kk_) do {                                                     \
    async16(Bp0 + (h_) * bhs + (kk_), sB + (nb_)*32768 + (h_)*16384 + tid16);          \
    async16(Bp1 + (h_) * bhs + (kk_), sB + (nb_)*32768 + (h_)*16384 + 8192 + tid16);   \
  } while (0)

  const int ch0 = ((lq ^ (lr & 7)) * 16);
  const int ch1 = (((4 + lq) ^ (lr & 7)) * 16);
  const int abase = (wm2 * 64 + lr) * 128;
  const int bbase = (wn4 * 32 + lr) * 128;

  f32x4 acc[8][4] = {};
  bf16x8 af[4][2], bfr[4][2];
  const int NT = K >> 6;

#define LOAD_A(mh_) do {                                                               \
    _Pragma("unroll")                                                                  \
    for (int i = 0; i < 4; i++) {                                                      \
      af[i][0] = *(const bf16x8*)(Ab + abase + (mh_)*16384 + i*2048 + ch0);            \
      af[i][1] = *(const bf16x8*)(Ab + abase + (mh_)*16384 + i*2048 + ch1);            \
    } } while (0)
#define LOAD_B(nh_) do {                                                               \
    _Pragma("unroll")                                                                  \
    for (int j = 0; j < 2; j++) {                                                      \
      bfr[(nh_)*2 + j][0] = *(const bf16x8*)(Bb + bbase + (nh_)*16384 + j*2048 + ch0); \
      bfr[(nh_)*2 + j][1] = *(const bf16x8*)(Bb + bbase + (nh_)*16384 + j*2048 + ch1); \
    } } while (0)
#define MFMA_Q(mh_, nh_) do {                                                          \
    __builtin_amdgcn_s_setprio(1);                                                     \
    _Pragma("unroll")                                                                  \
    for (int ks = 0; ks < 2; ks++)                                                     \
      _Pragma("unroll")                                                                \
      for (int i = 0; i < 4; i++)                                                      \
        _Pragma("unroll")                                                              \
        for (int j = 0; j < 2; j++)                                                    \
          acc[(mh_)*4 + i][(nh_)*2 + j] = __builtin_amdgcn_mfma_f32_16x16x32_bf16(     \
              af[i][ks], bfr[(nh_)*2 + j][ks], acc[(mh_)*4 + i][(nh_)*2 + j], 0, 0, 0);\
    __builtin_amdgcn_s_setprio(0);                                                     \
  } while (0)
#define SBAR() do { __builtin_amdgcn_sched_barrier(0);                                 \
    __builtin_amdgcn_s_barrier(); __builtin_amdgcn_sched_barrier(0); } while (0)
#define LGKM0() do { asm volatile("s_waitcnt lgkmcnt(0)" ::: "memory");                \
    __builtin_amdgcn_sched_barrier(0); } while (0)

  STAGE_A(0, 0, 0); STAGE_B(0, 0, 0); STAGE_B(1, 0, 0); STAGE_A(1, 0, 0);
  asm volatile("s_waitcnt vmcnt(4)" ::: "memory");
  SBAR();

  for (int T = 0; T < NT; ++T) {
    const int cb = T & 1, nb = cb ^ 1;
    const int kk = (T + 1) << 6;
    const bool st = (T + 1 < NT);
    const char* Ab = (const char*)As + cb * 32768;
    const char* Bb = (const char*)Bs + cb * 32768;
    LOAD_A(0); LOAD_B(0);
    if (st) { STAGE_A(0, nb, kk); STAGE_B(0, nb, kk); }
    SBAR(); LGKM0();
    MFMA_Q(0, 0);
    if (st) asm volatile("s_waitcnt vmcnt(6)" ::: "memory");
    else    asm volatile("s_waitcnt vmcnt(2)" ::: "memory");
    SBAR();
    LOAD_B(1);
    if (st) STAGE_B(1, nb, kk);
    SBAR(); LGKM0();
    MFMA_Q(0, 1);
    if (st) asm volatile("s_waitcnt vmcnt(6)" ::: "memory");
    else    asm volatile("s_waitcnt vmcnt(0)" ::: "memory");
    SBAR();
    LOAD_A(1);
    if (st) STAGE_A(1, nb, kk);
    SBAR(); LGKM0();
    MFMA_Q(1, 0);
    SBAR();
    MFMA_Q(1, 1);
    if (st) asm volatile("s_waitcnt vmcnt(4)" ::: "memory");
    SBAR();
  }
#undef STAGE_A
#undef STAGE_B
#undef LOAD_A
#undef LOAD_B
#undef MFMA_Q
#undef SBAR
#undef LGKM0

  const int lq4 = lq * 4;
  if (ROPE) {
    if (n0 < 4096) {
      const float invf0 = exp2f((float)(lr)      * -0.41524101186092029f);
      const float invf1 = exp2f((float)(16 + lr) * -0.41524101186092029f);
      #pragma unroll
      for (int mi = 0; mi < 8; mi++) {
        #pragma unroll
        for (int r = 0; r < 4; r++) {
          const long row = m0 + (mi >> 2) * 128 + wm2 * 64 + (mi & 3) * 16 + lq4 + r;
          const float s = (float)(int)(row & (SEQLEN - 1));
          __bf16* crow = (__bf16*)Cv + row * (long)ldc + n0 + wn4 * 64 + lr;
          #pragma unroll
          for (int nj = 0; nj < 2; nj++) {
            float x1 = acc[mi][nj][r], x2 = acc[mi][nj + 2][r];
            float ang = s * (nj ? invf1 : invf0);
            float sn, cs;
            __sincosf(ang, &sn, &cs);
            crow[nj * 16]      = (__bf16)(x1 * cs - x2 * sn);
            crow[nj * 16 + 32] = (__bf16)(x2 * cs + x1 * sn);
          }
        }
      }
    } else {
      #pragma unroll
      for (int mi = 0; mi < 8; mi++) {
        #pragma unroll
        for (int r = 0; r < 4; r++) {
          const long row = m0 + (mi >> 2) * 128 + wm2 * 64 + (mi & 3) * 16 + lq4 + r;
          __bf16* crow = (__bf16*)Cv + row * (long)ldc + n0 + wn4 * 64 + lr;
          #pragma unroll
          for (int njf = 0; njf < 4; njf++)
            crow[(njf >> 1) * 32 + (njf & 1) * 16] = (__bf16)acc[mi][njf][r];
        }
      }
    }
  } else {  // SILU
    #pragma unroll
    for (int mi = 0; mi < 8; mi++) {
      #pragma unroll
      for (int r = 0; r < 4; r++) {
        const long row = m0 + (mi >> 2) * 128 + wm2 * 64 + (mi & 3) * 16 + lq4 + r;
        #pragma unroll
        for (int nj = 0; nj < 2; nj++) {
          const long col = n0c + wn4 * 32 + nj * 16 + lr;
          float g = acc[mi][nj][r];
          float v = acc[mi][nj + 2][r];
          float sg = g / (1.0f + __expf(-g));
          ((__bf16*)Cv)[row * (long)ldc + col] = (__bf16)(sg * v);
        }
      }
    }
  }
}

// ---------------- flash attention v7: 128 q-rows/block, two stripes per wave --------
// Verified rounds 24-29: 515.0 / 496.8 / 497.5 / 513.8 / 496.7 / 496.9 us total.
// Each wave owns stripes A (q0+w*16) and B (q0+64+w*16); K/V loads, V-staging,
// barriers, kv loop SHARED; QK/softmax/P-write/PV duplicated per stripe with
// statically-named state. q0 multiple of 128 -> both stripes in one 512-causal-block;
// NT even. Pbb 16KB.
__global__ __launch_bounds__(256) void attn_kernel(const __bf16* __restrict__ qkv,
                                                   __bf16* __restrict__ ctx) {
  const int qt   = blockIdx.x;        // 0..15
  const int head = blockIdx.y;
  const int b    = blockIdx.z;
  const int w    = threadIdx.x >> 6;
  const int lane = threadIdx.x & 63;
  const int lr = lane & 15;
  const int lq = lane >> 4;
  const int q0   = qt * 128;
  const int blk0 = q0 & ~511;
  const int nkv  = q0 + 128 - blk0;   // 128..512, multiple of 128
  const int NT   = nkv >> 5;          // 4..16, even
  const long tok0 = (long)b * SEQLEN;

  const int qrowA = q0 + w * 16 + lr;
  const long qoffA = (tok0 + qrowA) * QKV_W + head * 64 + lq * 8;
  bf16x8 qa0 = *(const bf16x8*)(qkv + qoffA);
  bf16x8 qa1 = *(const bf16x8*)(qkv + qoffA + 32);
  const long qoffB = qoffA + (long)64 * QKV_W;
  bf16x8 qb0 = *(const bf16x8*)(qkv + qoffB);
  bf16x8 qb1 = *(const bf16x8*)(qkv + qoffB + 32);

  __shared__ __align__(16) char VTb[8192];    // V^T: d-rows of 128B, 2 kv-halves
  __shared__ __align__(16) char Pbb[16384];   // [w][stripe][16 q][128B]

  const __bf16* kp = qkv + (tok0 + blk0 + lr) * QKV_W + HID + head * 64 + lq * 8;
  const int skv = threadIdx.x & 31;
  const int sd0 = (threadIdx.x >> 5) * 8;
  const __bf16* vp = qkv + (tok0 + blk0 + skv) * QKV_W + 2 * HID + head * 64 + sd0;

  bf16x8 ka[2][2], kb[2][2];

#define LOADK(KN, tk) do { \
    KN[0][0] = *(const bf16x8*)(kp + (long)(tk) * QKV_W); \
    KN[0][1] = *(const bf16x8*)(kp + (long)(tk) * QKV_W + 32); \
    KN[1][0] = *(const bf16x8*)(kp + (long)((tk) + 16) * QKV_W); \
    KN[1][1] = *(const bf16x8*)(kp + (long)((tk) + 16) * QKV_W + 32); \
  } while (0)

#define WRITEV(vr_, hb_) do { \
    const int c_ = (hb_) * 4 + (skv >> 3); \
    char* vb_ = VTb + sd0 * 128 + ((skv & 7) * 2); \
    _Pragma("unroll") \
    for (int i_ = 0; i_ < 8; i_++) \
      *(__bf16*)(vb_ + i_ * 128 + ((c_ ^ i_) * 16)) = vr_[i_]; \
  } while (0)

  LOADK(ka, 0);
  {
    bf16x8 vr0 = *(const bf16x8*)(vp);
    WRITEV(vr0, 0);
  }
  __syncthreads();

  float mA[4], lA_[4], mB[4], lB_[4];
  f32x4 oA[4] = {}, oB[4] = {};
  #pragma unroll
  for (int r = 0; r < 4; r++) { mA[r] = -1e30f; lA_[r] = 0.0f; mB[r] = -1e30f; lB_[r] = 0.0f; }
  const int myrowA = q0 + w * 16 + lq * 4;
  const int myrowB = myrowA + 64;

  // one stripe's softmax + P-write: S regs (sx0,sx1) -> m/l update, P into Pbb stripe
#define SMAX_P(sx0, sx1, m_, l_, myrow_, soff_) do { \
    float p0[4], p1[4], alpha[4]; \
    _Pragma("unroll") \
    for (int r = 0; r < 4; r++) { \
      float v0 = sx0[r] * 0.125f, v1 = sx1[r] * 0.125f; \
      v0 = (kpos0_      <= (myrow_) + r) ? v0 : -1e30f; \
      v1 = (kpos0_ + 16 <= (myrow_) + r) ? v1 : -1e30f; \
      float mx = fmaxf(v0, v1); \
      mx = fmaxf(mx, __shfl_xor(mx, 1)); \
      mx = fmaxf(mx, __shfl_xor(mx, 2)); \
      mx = fmaxf(mx, __shfl_xor(mx, 4)); \
      mx = fmaxf(mx, __shfl_xor(mx, 8)); \
      float mn = fmaxf(m_[r], mx); \
      alpha[r] = __expf(m_[r] - mn); \
      m_[r] = mn; \
      p0[r] = __expf(v0 - mn); \
      p1[r] = __expf(v1 - mn); \
      float rs = p0[r] + p1[r]; \
      rs += __shfl_xor(rs, 1); rs += __shfl_xor(rs, 2); \
      rs += __shfl_xor(rs, 4); rs += __shfl_xor(rs, 8); \
      l_[r] = l_[r] * alpha[r] + rs; \
      alpha_##sx0[r] = alpha[r]; \
    } \
    { \
      char* pw_ = Pbb + w * 4096 + (soff_) + (lq * 4) * 128 + ((lr & 7) * 2); \
      const int cl_ = hb_ * 4 + (lr >> 3); \
      _Pragma("unroll") \
      for (int r = 0; r < 4; r++) { \
        const int q7_ = (lq * 4 + r) & 7; \
        *(__bf16*)(pw_ + r * 128 + (((cl_    ) ^ q7_) * 16)) = (__bf16)p0[r]; \
        *(__bf16*)(pw_ + r * 128 + (((cl_ + 2) ^ q7_) * 16)) = (__bf16)p1[r]; \
      } \
    } \
  } while (0)

#define ITER(t_, KC, KN) { \
    const int hb_ = (t_) & 1; \
    const int tkn_ = ((t_) + 1) * 32; \
    const bool more_ = ((t_) + 1 < NT); \
    bf16x8 vr_ = {}; \
    if (more_) { LOADK(KN, tkn_); vr_ = *(const bf16x8*)(vp + (long)tkn_ * QKV_W); } \
    f32x4 sa0 = {0.f,0.f,0.f,0.f}, sa1 = {0.f,0.f,0.f,0.f}; \
    f32x4 sb0 = {0.f,0.f,0.f,0.f}, sb1 = {0.f,0.f,0.f,0.f}; \
    sa0 = __builtin_amdgcn_mfma_f32_16x16x32_bf16(qa0, KC[0][0], sa0, 0, 0, 0); \
    sa0 = __builtin_amdgcn_mfma_f32_16x16x32_bf16(qa1, KC[0][1], sa0, 0, 0, 0); \
    sa1 = __builtin_amdgcn_mfma_f32_16x16x32_bf16(qa0, KC[1][0], sa1, 0, 0, 0); \
    sa1 = __builtin_amdgcn_mfma_f32_16x16x32_bf16(qa1, KC[1][1], sa1, 0, 0, 0); \
    sb0 = __builtin_amdgcn_mfma_f32_16x16x32_bf16(qb0, KC[0][0], sb0, 0, 0, 0); \
    sb0 = __builtin_amdgcn_mfma_f32_16x16x32_bf16(qb1, KC[0][1], sb0, 0, 0, 0); \
    sb1 = __builtin_amdgcn_mfma_f32_16x16x32_bf16(qb0, KC[1][0], sb1, 0, 0, 0); \
    sb1 = __builtin_amdgcn_mfma_f32_16x16x32_bf16(qb1, KC[1][1], sb1, 0, 0, 0); \
    const int kpos0_ = blk0 + (t_) * 32 + lr; \
    float alpha_sa0[4], alpha_sb0[4]; \
    SMAX_P(sa0, sa1, mA, lA_, myrowA, 0); \
    SMAX_P(sb0, sb1, mB, lB_, myrowB, 2048); \
    _Pragma("unroll") \
    for (int dt = 0; dt < 4; dt++) \
      _Pragma("unroll") \
      for (int r = 0; r < 4; r++) { \
        oA[dt][r] *= alpha_sa0[r]; \
        oB[dt][r] *= alpha_sb0[r]; \
      } \
    asm volatile("s_waitcnt lgkmcnt(0)" ::: "memory"); \
    const int swz_ = ((hb_ * 4 + lq) ^ (lr & 7)) * 16; \
    bf16x8 pfA_ = *(const bf16x8*)(Pbb + w * 4096 + lr * 128 + swz_); \
    bf16x8 pfB_ = *(const bf16x8*)(Pbb + w * 4096 + 2048 + lr * 128 + swz_); \
    _Pragma("unroll") \
    for (int dt = 0; dt < 4; dt++) { \
      bf16x8 vf_ = *(const bf16x8*)(VTb + (dt * 16 + lr) * 128 + swz_); \
      oA[dt] = __builtin_amdgcn_mfma_f32_16x16x32_bf16(pfA_, vf_, oA[dt], 0, 0, 0); \
      oB[dt] = __builtin_amdgcn_mfma_f32_16x16x32_bf16(pfB_, vf_, oB[dt], 0, 0, 0); \
    } \
    __syncthreads(); \
    if (more_) WRITEV(vr_, hb_ ^ 1); \
    __syncthreads(); \
  }

  for (int t2 = 0; t2 < NT; t2 += 2) {
    ITER(t2, ka, kb)
    ITER(t2 + 1, kb, ka)
  }
#undef ITER
#undef SMAX_P
#undef LOADK
#undef WRITEV

  #pragma unroll
  for (int r = 0; r < 4; r++) {
    float invA = 1.0f / lA_[r];
    float invB = 1.0f / lB_[r];
    long obaseA = (tok0 + myrowA + r) * HID + head * 64;
    long obaseB = (tok0 + myrowB + r) * HID + head * 64;
    #pragma unroll
    for (int dt = 0; dt < 4; dt++) {
      ctx[obaseA + dt * 16 + lr] = (__bf16)(oA[dt][r] * invA);
      ctx[obaseB + dt * 16 + lr] = (__bf16)(oB[dt][r] * invB);
    }
  }
}

extern "C" void kernel_launch(void* const* d_in, const int* in_sizes, int n_in,
                              void* d_out, int out_size, void* d_ws, size_t ws_size,
                              hipStream_t stream) {
  const float* x      = (const float*)d_in[0];
  const float* anw    = (const float*)d_in[1];
  const float* fnw    = (const float*)d_in[2];
  const float* w_qkv  = (const float*)d_in[3];
  const float* w_o    = (const float*)d_in[4];
  const float* w_up   = (const float*)d_in[5];
  const float* w_down = (const float*)d_in[6];
  float* out = (float*)d_out;

  const size_t MiB = 1048576;
  char* wsb = (char*)d_ws;
  __bf16* ABUF = (__bf16*)wsb;                   // 16 MiB: h1 / ctx / h2
  __bf16* QKV  = (__bf16*)(wsb + 16 * MiB);      // 48 MiB: qkv; later act (32 MiB)
  __bf16* ACT  = QKV;

  // Persistent converted-weight layout (needs 144 MiB + flags); falls back to the
  // old transient single-scratch layout if the workspace is too small.
  const size_t NEED = 144 * MiB + 64;
  const bool persist = (ws_size >= NEED);
  __bf16 *WQKV, *WO, *WUP, *WDOWN;
  unsigned* CTL = nullptr;
  if (persist) {
    WQKV  = (__bf16*)(wsb + 64 * MiB);   // 24 MiB
    WO    = (__bf16*)(wsb + 88 * MiB);   //  8 MiB
    WUP   = (__bf16*)(wsb + 96 * MiB);   // 32 MiB
    WDOWN = (__bf16*)(wsb + 128 * MiB);  // 16 MiB
    CTL   = (unsigned*)(wsb + 144 * MiB);
  } else {
    __bf16* WBUF = (__bf16*)(wsb + (size_t)83886080);
    WQKV = WO = WUP = WDOWN = WBUF;
  }

  // attention half
  rmsnorm_kernel<<<TOKENS, 256, 0, stream>>>(x, anw, ABUF);
  cvt_kernel<<<2048, 256, 0, stream>>>(w_qkv, WQKV, QKV_W * HID / 4,
                                       persist ? CTL + 0 : nullptr);
  // Q,K (rope fused) via gemm8p v3: grid 16x16 = 256 blocks = exactly 1 round
  gemm8p<true, false><<<dim3(4096 / 256, TOKENS / 256), 512, 0, stream>>>(
      ABUF, HID, WQKV, HID, (void*)QKV, QKV_W, HID);
  // V (plain) via old kernel: grid 16x32 = 512 blocks, full chip
  gemm_bt<true, false, false, false><<<dim3(HID / 128, TOKENS / 128), 256, 0, stream>>>(
      ABUF, HID, WQKV + (size_t)4096 * HID, HID, (void*)(QKV + 4096), QKV_W, nullptr, HID);
  attn_kernel<<<dim3(SEQLEN / 128, 32, 2), 256, 0, stream>>>(QKV, ABUF);
  cvt_kernel<<<2048, 256, 0, stream>>>(w_o, WO, HID * HID / 4,
                                       persist ? CTL + 1 : nullptr);
  gemm_bt<false, true, false, false><<<dim3(HID / 128, TOKENS / 128), 256, 0, stream>>>(
      ABUF, HID, WO, HID, (void*)out, HID, x, HID);   // out = x + ctx@w_o^T

  // ffn half
  rmsnorm_kernel<<<TOKENS, 256, 0, stream>>>(out, fnw, ABUF);
  cvt_kernel<<<2048, 256, 0, stream>>>(w_up, WUP, UP_W * HID / 4,
                                       persist ? CTL + 2 : nullptr);
  // fused up+silu via gemm8p v3: grid 32x16 = 512 blocks = 2 exact rounds
  gemm8p<false, true><<<dim3(INTER_ / 128, TOKENS / 256), 512, 0, stream>>>(
      ABUF, HID, WUP, HID, (void*)ACT, INTER_, HID);
  cvt_kernel<<<2048, 256, 0, stream>>>(w_down, WDOWN, HID * INTER_ / 4,
                                       persist ? CTL + 3 : nullptr);
  gemm_bt<false, true, false, false><<<dim3(HID / 128, TOKENS / 128), 256, 0, stream>>>(
      ACT, INTER_, WDOWN, INTER_, (void*)out, HID, out, INTER_); // out += act@w_down^T
}